// Round 9
// baseline (67.833 us; speedup 1.0000x reference)
//
#include <hip/hip_runtime.h>

#define DIMS 128
#define KTOP 16
#define SMAX 2048     // max MAXG supported by top-k kernel
#define SLICE 128     // candidates per score block
#define CK 132        // s_keyT row stride in dwords (16B-aligned, conflict-free)
#define CQ 20         // s_qT row stride in dwords (16B-aligned)
#define QT 16         // queries per chunk
#define NTHR 128

__device__ __forceinline__ unsigned long long packsim(float v, int g) {
    unsigned u = __float_as_uint(v);
    u = (u & 0x80000000u) ? ~u : (u | 0x80000000u);
    return ((unsigned long long)u << 32) | (unsigned)(0xFFFFFFFFu - (unsigned)g);
}

// ---------------- Kernel 0: zero + bucket queries, single block ----------------
__global__ __launch_bounds__(1024)
void bucket_kernel(const int* __restrict__ hard_assign,
                   int* __restrict__ qcount, int* __restrict__ qlist, int B, int P)
{
    const int t = threadIdx.x;
    for (int i = t; i < P; i += 1024) qcount[i] = 0;
    __syncthreads();
    for (int b = t; b < B; b += 1024) {
        const int p = hard_assign[b];
        const int slot = atomicAdd(&qcount[p], 1);
        qlist[(size_t)p * B + slot] = b;
    }
}

// ---- Kernel 1: register-tiled GEMM: 16 queries x 128 candidates per block ----
// Thread tile 4q x 4c; keys/queries transposed in LDS; no cross-lane reduces.
__global__ __launch_bounds__(NTHR)
void score_kernel(const float* __restrict__ query,
                  const float* __restrict__ keys,
                  const int*   __restrict__ cached_groups,
                  const int*   __restrict__ qcount,
                  const int*   __restrict__ qlist,
                  float* __restrict__ sims,
                  int B, int N, int MAXG, int nslice)
{
    extern __shared__ float smem[];
    float* s_keyT = smem;                      // [DIMS][CK]  (d-major, c minor)
    float* s_qT   = s_keyT + DIMS * CK;        // [DIMS][CQ]
    float* s_inv  = s_qT + DIMS * CQ;          // [SLICE]
    int*   s_g    = (int*)(s_inv + SLICE);     // [SLICE]
    int*   s_qb   = s_g + SLICE;               // [QT]

    const int p = blockIdx.x / nslice;
    const int s = blockIdx.x % nslice;
    const int cnt = qcount[p];
    if (cnt == 0) return;

    const int t = threadIdx.x;
    const int base = s * SLICE;
    const int* gp = cached_groups + (size_t)p * MAXG;
    const int* ql = qlist + (size_t)p * B;

    // ---- stage keys: thread t owns candidate row t; write transposed.
    // LDS writes: lanes are consecutive c at fixed d -> stride-1, conflict-free.
    {
        const int cand = (base + t < MAXG) ? gp[base + t] : -1;
        s_g[t] = cand;
        const int sf = cand < 0 ? 0 : (cand > N - 1 ? N - 1 : cand);
        const float* kr = keys + (size_t)sf * DIMS;
        float ks = 0.0f;
        #pragma unroll
        for (int h = 0; h < 4; ++h) {          // 4 batches of 32 dims (8 b128 MLP)
            float4 v[8];
            #pragma unroll
            for (int i = 0; i < 8; ++i)
                v[i] = *(const float4*)(kr + h * 32 + i * 4);
            #pragma unroll
            for (int i = 0; i < 8; ++i) {
                const int d = h * 32 + i * 4;
                ks += v[i].x * v[i].x + v[i].y * v[i].y
                    + v[i].z * v[i].z + v[i].w * v[i].w;
                s_keyT[(d + 0) * CK + t] = v[i].x;
                s_keyT[(d + 1) * CK + t] = v[i].y;
                s_keyT[(d + 2) * CK + t] = v[i].z;
                s_keyT[(d + 3) * CK + t] = v[i].w;
            }
        }
        s_inv[t] = 1.0f / fmaxf(sqrtf(ks), 1e-12f);
    }

    const int qrow = t >> 5;       // 0..3
    const int ccol = t & 31;       // 0..31
    const int q0 = qrow * 4;
    const int c0 = ccol * 4;

    for (int qbase = 0; qbase < cnt; qbase += QT) {
        // ---- stage QT query rows transposed: thread (q=t&15, dblk=t>>4) ----
        {
            const int q    = t & 15;
            const int dblk = t >> 4;           // 0..7, 16 dims each
            const int ii = qbase + q;
            const int sq = ql[(ii < cnt) ? ii : (cnt - 1)];   // dup tail, masked
            if (dblk == 0) s_qb[q] = sq;
            const float* qr = query + (size_t)sq * DIMS + dblk * 16;
            #pragma unroll
            for (int i = 0; i < 4; ++i) {
                const float4 v = *(const float4*)(qr + i * 4);
                const int d = dblk * 16 + i * 4;
                s_qT[(d + 0) * CQ + q] = v.x;
                s_qT[(d + 1) * CQ + q] = v.y;
                s_qT[(d + 2) * CQ + q] = v.z;
                s_qT[(d + 3) * CQ + q] = v.w;
            }
        }
        __syncthreads();   // first iter: also covers key staging

        float acc[4][4];
        #pragma unroll
        for (int a = 0; a < 4; ++a)
            #pragma unroll
            for (int bb = 0; bb < 4; ++bb) acc[a][bb] = 0.0f;

        // A-read: b128 broadcast (2 addrs/wave); B-read: b128 linear (conflict-free)
        #pragma unroll 4
        for (int k = 0; k < DIMS; ++k) {
            const float4 aq = *(const float4*)&s_qT[k * CQ + q0];
            const float4 bk = *(const float4*)&s_keyT[k * CK + c0];
            acc[0][0] += aq.x * bk.x; acc[0][1] += aq.x * bk.y;
            acc[0][2] += aq.x * bk.z; acc[0][3] += aq.x * bk.w;
            acc[1][0] += aq.y * bk.x; acc[1][1] += aq.y * bk.y;
            acc[1][2] += aq.y * bk.z; acc[1][3] += aq.y * bk.w;
            acc[2][0] += aq.z * bk.x; acc[2][1] += aq.z * bk.y;
            acc[2][2] += aq.z * bk.z; acc[2][3] += aq.z * bk.w;
            acc[3][0] += aq.w * bk.x; acc[3][1] += aq.w * bk.y;
            acc[3][2] += aq.w * bk.z; acc[3][3] += aq.w * bk.w;
        }

        // ---- epilogue: post-scale by key inv-norm, mask invalid, coalesced f4 ----
        const float4 inv = *(const float4*)&s_inv[c0];
        const int4   gv  = *(const int4*)&s_g[c0];
        #pragma unroll
        for (int qi = 0; qi < 4; ++qi) {
            const int ii = qbase + q0 + qi;
            if (ii < cnt) {
                const int b = s_qb[q0 + qi];
                float4 o;
                o.x = (gv.x >= 0) ? acc[qi][0] * inv.x : -1.0e9f;
                o.y = (gv.y >= 0) ? acc[qi][1] * inv.y : -1.0e9f;
                o.z = (gv.z >= 0) ? acc[qi][2] * inv.z : -1.0e9f;
                o.w = (gv.w >= 0) ? acc[qi][3] * inv.w : -1.0e9f;
                float* dst = sims + (size_t)b * MAXG + base + c0;
                if (base + c0 + 3 < MAXG) {
                    *(float4*)dst = o;
                } else {
                    if (base + c0 + 0 < MAXG) dst[0] = o.x;
                    if (base + c0 + 1 < MAXG) dst[1] = o.y;
                    if (base + c0 + 2 < MAXG) dst[2] = o.z;
                }
            }
        }

        if (qbase + QT < cnt) __syncthreads();   // protect s_qT rewrite
    }
}

// ---------------- Kernel 2: top-16 per query + output gather ----------------
__global__ __launch_bounds__(256)
void topk_gather_kernel(const float* __restrict__ keys,
                        const float* __restrict__ vals,
                        const float* __restrict__ labels,
                        const int*   __restrict__ hard_assign,
                        const int*   __restrict__ cached_groups,
                        const int*   __restrict__ group_sizes,
                        const float* __restrict__ sims,
                        float* __restrict__ out,
                        int B, int MAXG)
{
    const int b = blockIdx.x, t = threadIdx.x;
    const int lane = t & 63, w = t >> 6;
    const int sub = t & 15, cg = t >> 4;

    __shared__ unsigned long long s_merge[64];
    __shared__ int s_wing[KTOP];

    const int p = hard_assign[b];
    const int grpsz = group_sizes[p];
    const bool normal = (grpsz >= KTOP);
    const int* gptr = cached_groups + (size_t)p * MAXG;
    const float* simrow = sims + (size_t)b * MAXG;

    // phase A: wave-local top-16 of 512 values, shuffle-only
    unsigned long long mk[SMAX / 256];
    #pragma unroll
    for (int j = 0; j < SMAX / 256; ++j) {
        const int g = w * (SMAX / 4) + j * 64 + lane;
        const float v = (g < MAXG) ? simrow[g] : -3.0e38f;
        mk[j] = packsim(v, g);
    }
    #pragma unroll 1
    for (int r = 0; r < KTOP; ++r) {
        unsigned long long m = mk[0];
        #pragma unroll
        for (int j = 1; j < SMAX / 256; ++j) m = (mk[j] > m) ? mk[j] : m;
        #pragma unroll
        for (int off = 1; off < 64; off <<= 1) {
            unsigned long long o = __shfl_xor(m, off, 64);
            m = (o > m) ? o : m;
        }
        if (lane == 0) s_merge[w * KTOP + r] = m;
        #pragma unroll
        for (int j = 0; j < SMAX / 256; ++j) if (mk[j] == m) mk[j] = 0ull;
    }
    __syncthreads();

    // phase B: wave 0 merges 64 survivors -> global top-16 in order
    if (w == 0) {
        unsigned long long u = s_merge[lane];
        #pragma unroll 1
        for (int r = 0; r < KTOP; ++r) {
            unsigned long long m = u;
            #pragma unroll
            for (int off = 1; off < 64; off <<= 1) {
                unsigned long long o = __shfl_xor(m, off, 64);
                m = (o > m) ? o : m;
            }
            if (lane == 0)
                s_wing[r] = (int)(0xFFFFFFFFu - (unsigned)(m & 0xFFFFFFFFull));
            if (u == m) u = 0ull;
        }
    }
    __syncthreads();

    // outputs: group cg handles winner #cg
    const int g    = s_wing[cg];
    const int cand = gptr[g];
    const int idx  = cand < 0 ? 0 : cand;

    const size_t BK = (size_t)B * KTOP;
    float* out_nk = out;
    float* out_nv = out + BK * DIMS;
    float* out_nl = out + 2 * BK * DIMS;
    float* out_id = out_nl + BK;

    const size_t od = ((size_t)b * KTOP + cg) * DIMS + sub * 8;
    if (normal) {
        const float* kr = keys + (size_t)idx * DIMS + sub * 8;
        const float* vr = vals + (size_t)idx * DIMS + sub * 8;
        *(float4*)(out_nk + od)     = *(const float4*)(kr);
        *(float4*)(out_nk + od + 4) = *(const float4*)(kr + 4);
        *(float4*)(out_nv + od)     = *(const float4*)(vr);
        *(float4*)(out_nv + od + 4) = *(const float4*)(vr + 4);
        if (sub == 0) {
            out_nl[(size_t)b * KTOP + cg] = labels[idx];
            out_id[(size_t)b * KTOP + cg] = (float)idx;
        }
    } else {
        const float4 z = make_float4(0.f, 0.f, 0.f, 0.f);
        *(float4*)(out_nk + od)     = z;
        *(float4*)(out_nk + od + 4) = z;
        *(float4*)(out_nv + od)     = z;
        *(float4*)(out_nv + od + 4) = z;
        if (sub == 0) {
            out_nl[(size_t)b * KTOP + cg] = 0.0f;
            out_id[(size_t)b * KTOP + cg] = 0.0f;
        }
    }
}

extern "C" void kernel_launch(void* const* d_in, const int* in_sizes, int n_in,
                              void* d_out, int out_size, void* d_ws, size_t ws_size,
                              hipStream_t stream) {
    const float* query  = (const float*)d_in[0];
    const float* keys   = (const float*)d_in[1];
    const float* vals   = (const float*)d_in[2];
    const float* labels = (const float*)d_in[3];
    const int* hard_assign   = (const int*)d_in[4];
    const int* cached_groups = (const int*)d_in[5];
    const int* group_sizes   = (const int*)d_in[6];

    const int B = in_sizes[0] / DIMS;
    const int N = in_sizes[1] / DIMS;
    const int P = in_sizes[6];
    const int MAXG = in_sizes[5] / P;
    const int nslice = (MAXG + SLICE - 1) / SLICE;

    float* sims  = (float*)d_ws;                                // B*MAXG floats
    int* qcount  = (int*)((char*)d_ws + (size_t)B * MAXG * 4);  // P ints
    int* qlist   = qcount + P;                                  // P*B ints

    const int smem_bytes = (DIMS * CK + DIMS * CQ + SLICE + SLICE + QT) * 4;
    static bool attr_set = false;
    if (!attr_set) {
        (void)hipFuncSetAttribute((const void*)score_kernel,
                                  hipFuncAttributeMaxDynamicSharedMemorySize,
                                  smem_bytes);
        attr_set = true;
    }

    bucket_kernel<<<1, 1024, 0, stream>>>(hard_assign, qcount, qlist, B, P);

    score_kernel<<<P * nslice, NTHR, smem_bytes, stream>>>(
        query, keys, cached_groups, qcount, qlist, sims, B, N, MAXG, nslice);

    topk_gather_kernel<<<B, 256, 0, stream>>>(
        keys, vals, labels, hard_assign, cached_groups, group_sizes, sims,
        (float*)d_out, B, MAXG);
}

// Round 10
// 60.156 us; speedup vs baseline: 1.1276x; 1.1276x over previous
//
#include <hip/hip_runtime.h>

#define DIMS 128
#define KTOP 16
#define SMAX 2048     // max MAXG supported by top-k kernel
#define SLICE 64      // candidates per score block
#define CK 64         // s_keyT row stride in dwords (unpadded; 2-way = free)
#define CQ 16         // s_qT row stride in dwords
#define QT 16         // queries per chunk
#define NTHR 128

__device__ __forceinline__ unsigned long long packsim(float v, int g) {
    unsigned u = __float_as_uint(v);
    u = (u & 0x80000000u) ? ~u : (u | 0x80000000u);
    return ((unsigned long long)u << 32) | (unsigned)(0xFFFFFFFFu - (unsigned)g);
}

// ---------------- Kernel 0: zero + bucket queries, single block ----------------
__global__ __launch_bounds__(1024)
void bucket_kernel(const int* __restrict__ hard_assign,
                   int* __restrict__ qcount, int* __restrict__ qlist, int B, int P)
{
    const int t = threadIdx.x;
    for (int i = t; i < P; i += 1024) qcount[i] = 0;
    __syncthreads();
    for (int b = t; b < B; b += 1024) {
        const int p = hard_assign[b];
        const int slot = atomicAdd(&qcount[p], 1);
        qlist[(size_t)p * B + slot] = b;
    }
}

// ---- Kernel 1: register-tiled GEMM, 16 queries x 64 candidates per block ----
// 3 blocks/CU resident (40.6 KB LDS); thread tile 2q x 4c; no shuffles in loop.
__global__ __launch_bounds__(NTHR)
void score_kernel(const float* __restrict__ query,
                  const float* __restrict__ keys,
                  const int*   __restrict__ cached_groups,
                  const int*   __restrict__ qcount,
                  const int*   __restrict__ qlist,
                  float* __restrict__ sims,
                  int B, int N, int MAXG, int nslice)
{
    __shared__ float s_keyT[DIMS * CK];   // 32 KB, [d][c]
    __shared__ float s_qT[DIMS * CQ];     //  8 KB, [d][q]
    __shared__ float s_inv[SLICE];
    __shared__ int   s_g[SLICE];
    __shared__ int   s_qb[QT];

    const int p = blockIdx.x / nslice;
    const int s = blockIdx.x % nslice;
    const int cnt = qcount[p];
    if (cnt == 0) return;

    const int t = threadIdx.x;
    const int base = s * SLICE;
    const int* gp = cached_groups + (size_t)p * MAXG;
    const int* ql = qlist + (size_t)p * B;

    // ---- stage keys: 2 threads per candidate row (64 dims each) ----
    {
        const int r    = t >> 1;          // candidate 0..63
        const int half = t & 1;           // dim half
        const int cand = (base + r < MAXG) ? gp[base + r] : -1;
        if (half == 0) s_g[r] = cand;
        const int sf = cand < 0 ? 0 : (cand > N - 1 ? N - 1 : cand);
        const float* kr = keys + (size_t)sf * DIMS + half * 64;
        float ks = 0.0f;
        #pragma unroll
        for (int h = 0; h < 2; ++h) {     // 2 batches of 8 b128 loads (deep MLP)
            float4 v[8];
            #pragma unroll
            for (int i = 0; i < 8; ++i)
                v[i] = *(const float4*)(kr + h * 32 + i * 4);
            #pragma unroll
            for (int i = 0; i < 8; ++i) {
                const int d = half * 64 + h * 32 + i * 4;
                ks += v[i].x * v[i].x + v[i].y * v[i].y
                    + v[i].z * v[i].z + v[i].w * v[i].w;
                s_keyT[(d + 0) * CK + r] = v[i].x;
                s_keyT[(d + 1) * CK + r] = v[i].y;
                s_keyT[(d + 2) * CK + r] = v[i].z;
                s_keyT[(d + 3) * CK + r] = v[i].w;
            }
        }
        ks += __shfl_xor(ks, 1, 64);      // pair-reduce the two halves
        if (half == 0) s_inv[r] = 1.0f / fmaxf(sqrtf(ks), 1e-12f);
    }

    const int q0 = (t >> 4) * 2;          // 0,2,..,14
    const int c0 = (t & 15) * 4;          // 0,4,..,60

    for (int qbase = 0; qbase < cnt; qbase += QT) {
        // ---- stage QT query rows transposed: thread (q=t&15, dblk=t>>4) ----
        {
            const int q    = t & 15;
            const int dblk = t >> 4;      // 0..7, 16 dims each
            const int ii = qbase + q;
            const int sq = ql[(ii < cnt) ? ii : (cnt - 1)];   // dup tail, masked
            if (dblk == 0) s_qb[q] = sq;
            const float* qr = query + (size_t)sq * DIMS + dblk * 16;
            #pragma unroll
            for (int i = 0; i < 4; ++i) {
                const float4 v = *(const float4*)(qr + i * 4);
                const int d = dblk * 16 + i * 4;
                s_qT[(d + 0) * CQ + q] = v.x;
                s_qT[(d + 1) * CQ + q] = v.y;
                s_qT[(d + 2) * CQ + q] = v.z;
                s_qT[(d + 3) * CQ + q] = v.w;
            }
        }
        __syncthreads();   // first iter: also covers key staging

        float acc[2][4];
        #pragma unroll
        for (int a = 0; a < 2; ++a)
            #pragma unroll
            for (int bb = 0; bb < 4; ++bb) acc[a][bb] = 0.0f;

        // A-read: b64 broadcast (1 addr per quarter-wave); B-read: b128 2-way (free)
        #pragma unroll 8
        for (int k = 0; k < DIMS; ++k) {
            const float2 aq = *(const float2*)&s_qT[k * CQ + q0];
            const float4 bk = *(const float4*)&s_keyT[k * CK + c0];
            acc[0][0] += aq.x * bk.x; acc[0][1] += aq.x * bk.y;
            acc[0][2] += aq.x * bk.z; acc[0][3] += aq.x * bk.w;
            acc[1][0] += aq.y * bk.x; acc[1][1] += aq.y * bk.y;
            acc[1][2] += aq.y * bk.z; acc[1][3] += aq.y * bk.w;
        }

        // ---- epilogue: scale by key inv-norm, mask invalid, coalesced f4 ----
        const float4 inv = *(const float4*)&s_inv[c0];
        const int4   gv  = *(const int4*)&s_g[c0];
        #pragma unroll
        for (int qi = 0; qi < 2; ++qi) {
            const int ii = qbase + q0 + qi;
            if (ii < cnt) {
                const int b = s_qb[q0 + qi];
                float4 o;
                o.x = (gv.x >= 0) ? acc[qi][0] * inv.x : -1.0e9f;
                o.y = (gv.y >= 0) ? acc[qi][1] * inv.y : -1.0e9f;
                o.z = (gv.z >= 0) ? acc[qi][2] * inv.z : -1.0e9f;
                o.w = (gv.w >= 0) ? acc[qi][3] * inv.w : -1.0e9f;
                float* dst = sims + (size_t)b * MAXG + base + c0;
                if (base + c0 + 3 < MAXG) {
                    *(float4*)dst = o;
                } else {
                    if (base + c0 + 0 < MAXG) dst[0] = o.x;
                    if (base + c0 + 1 < MAXG) dst[1] = o.y;
                    if (base + c0 + 2 < MAXG) dst[2] = o.z;
                }
            }
        }

        if (qbase + QT < cnt) __syncthreads();   // protect s_qT rewrite
    }
}

// ---------------- Kernel 2: top-16 per query + output gather ----------------
__global__ __launch_bounds__(256)
void topk_gather_kernel(const float* __restrict__ keys,
                        const float* __restrict__ vals,
                        const float* __restrict__ labels,
                        const int*   __restrict__ hard_assign,
                        const int*   __restrict__ cached_groups,
                        const int*   __restrict__ group_sizes,
                        const float* __restrict__ sims,
                        float* __restrict__ out,
                        int B, int MAXG)
{
    const int b = blockIdx.x, t = threadIdx.x;
    const int lane = t & 63, w = t >> 6;
    const int sub = t & 15, cg = t >> 4;

    __shared__ unsigned long long s_merge[64];
    __shared__ int s_wing[KTOP];

    const int p = hard_assign[b];
    const int grpsz = group_sizes[p];
    const bool normal = (grpsz >= KTOP);
    const int* gptr = cached_groups + (size_t)p * MAXG;
    const float* simrow = sims + (size_t)b * MAXG;

    // phase A: wave-local top-16 of 512 values, shuffle-only
    unsigned long long mk[SMAX / 256];
    #pragma unroll
    for (int j = 0; j < SMAX / 256; ++j) {
        const int g = w * (SMAX / 4) + j * 64 + lane;
        const float v = (g < MAXG) ? simrow[g] : -3.0e38f;
        mk[j] = packsim(v, g);
    }
    #pragma unroll 1
    for (int r = 0; r < KTOP; ++r) {
        unsigned long long m = mk[0];
        #pragma unroll
        for (int j = 1; j < SMAX / 256; ++j) m = (mk[j] > m) ? mk[j] : m;
        #pragma unroll
        for (int off = 1; off < 64; off <<= 1) {
            unsigned long long o = __shfl_xor(m, off, 64);
            m = (o > m) ? o : m;
        }
        if (lane == 0) s_merge[w * KTOP + r] = m;
        #pragma unroll
        for (int j = 0; j < SMAX / 256; ++j) if (mk[j] == m) mk[j] = 0ull;
    }
    __syncthreads();

    // phase B: wave 0 merges 64 survivors -> global top-16 in order
    if (w == 0) {
        unsigned long long u = s_merge[lane];
        #pragma unroll 1
        for (int r = 0; r < KTOP; ++r) {
            unsigned long long m = u;
            #pragma unroll
            for (int off = 1; off < 64; off <<= 1) {
                unsigned long long o = __shfl_xor(m, off, 64);
                m = (o > m) ? o : m;
            }
            if (lane == 0)
                s_wing[r] = (int)(0xFFFFFFFFu - (unsigned)(m & 0xFFFFFFFFull));
            if (u == m) u = 0ull;
        }
    }
    __syncthreads();

    // outputs: group cg handles winner #cg
    const int g    = s_wing[cg];
    const int cand = gptr[g];
    const int idx  = cand < 0 ? 0 : cand;

    const size_t BK = (size_t)B * KTOP;
    float* out_nk = out;
    float* out_nv = out + BK * DIMS;
    float* out_nl = out + 2 * BK * DIMS;
    float* out_id = out_nl + BK;

    const size_t od = ((size_t)b * KTOP + cg) * DIMS + sub * 8;
    if (normal) {
        const float* kr = keys + (size_t)idx * DIMS + sub * 8;
        const float* vr = vals + (size_t)idx * DIMS + sub * 8;
        *(float4*)(out_nk + od)     = *(const float4*)(kr);
        *(float4*)(out_nk + od + 4) = *(const float4*)(kr + 4);
        *(float4*)(out_nv + od)     = *(const float4*)(vr);
        *(float4*)(out_nv + od + 4) = *(const float4*)(vr + 4);
        if (sub == 0) {
            out_nl[(size_t)b * KTOP + cg] = labels[idx];
            out_id[(size_t)b * KTOP + cg] = (float)idx;
        }
    } else {
        const float4 z = make_float4(0.f, 0.f, 0.f, 0.f);
        *(float4*)(out_nk + od)     = z;
        *(float4*)(out_nk + od + 4) = z;
        *(float4*)(out_nv + od)     = z;
        *(float4*)(out_nv + od + 4) = z;
        if (sub == 0) {
            out_nl[(size_t)b * KTOP + cg] = 0.0f;
            out_id[(size_t)b * KTOP + cg] = 0.0f;
        }
    }
}

extern "C" void kernel_launch(void* const* d_in, const int* in_sizes, int n_in,
                              void* d_out, int out_size, void* d_ws, size_t ws_size,
                              hipStream_t stream) {
    const float* query  = (const float*)d_in[0];
    const float* keys   = (const float*)d_in[1];
    const float* vals   = (const float*)d_in[2];
    const float* labels = (const float*)d_in[3];
    const int* hard_assign   = (const int*)d_in[4];
    const int* cached_groups = (const int*)d_in[5];
    const int* group_sizes   = (const int*)d_in[6];

    const int B = in_sizes[0] / DIMS;
    const int N = in_sizes[1] / DIMS;
    const int P = in_sizes[6];
    const int MAXG = in_sizes[5] / P;
    const int nslice = (MAXG + SLICE - 1) / SLICE;

    float* sims  = (float*)d_ws;                                // B*MAXG floats
    int* qcount  = (int*)((char*)d_ws + (size_t)B * MAXG * 4);  // P ints
    int* qlist   = qcount + P;                                  // P*B ints

    bucket_kernel<<<1, 1024, 0, stream>>>(hard_assign, qcount, qlist, B, P);

    score_kernel<<<P * nslice, NTHR, 0, stream>>>(
        query, keys, cached_groups, qcount, qlist, sims, B, N, MAXG, nslice);

    topk_gather_kernel<<<B, 256, 0, stream>>>(
        keys, vals, labels, hard_assign, cached_groups, group_sizes, sims,
        (float*)d_out, B, MAXG);
}